// Round 11
// baseline (208.150 us; speedup 1.0000x reference)
//
#include <hip/hip_runtime.h>

// KNN argmin over L2, round 11.
//  - phaseA: R10 skeleton + (a) Q-fragments PINNED in VGPRs via empty
//    asm volatile "+v" (R6/R10 showed the compiler rematerializes
//    loop-invariant global loads every step: VGPR=84 << 130 live set);
//    (b) MFMA C initialized to -0.5*sq so a = cross - sq/2 accumulates
//    in-chain; epilogue is pure max-tracking (key = -2*max at block write).
//  - phaseB: no S_T / no transpose kernel. Candidate 256-support blocks are
//    rescored by staging 64x64 fp32 chunks from ROW-MAJOR S into padded LDS
//    (contiguous 16KB coalesced loads; padded readback is 2-way = free;
//    same-wave DS ordering needs no barrier). 3 launches total.
//  - k_prep unchanged (S+Q panels + sqS; panel layout R8-proven).
//
// Filter certification unchanged: 3-term split (sh.qh + sl.qh + sh.ql),
// key error <= ~0.014 << EPS=0.05 => rescore set provably contains the
// true first-argmin support. Phase B compares exact fp32 keys with
// strict-< ascending scan + lexicographic cross-lane reduce => np.argmin
// first-index semantics.

#define NTOT   16384
#define DIM    64
#define SBLK   256                // bmin granularity
#define NSB    (NTOT / SBLK)      // 64
#define EPS    0.05f
#define FLT_BIG 3.4e38f

typedef __attribute__((ext_vector_type(8))) short short8;
typedef __attribute__((ext_vector_type(4))) float float4v;

__device__ __forceinline__ ushort bf16_rne(float x) {
  unsigned u = __float_as_uint(x);
  return (ushort)((u + 0x7FFF + ((u >> 16) & 1)) >> 16);
}

// Opaque def: forbids rematerialization of v from memory (forces residency).
__device__ __forceinline__ void pin8(short8& v) {
  asm volatile("" : "+v"(v));
}

// ---------------------------------------------------------------------------
// Fused prep: blocks 0..255 -> S (panels + sqS); blocks 256..511 -> Q.
// Panel layout (16-row panels, phase A lane order, R8-proven):
//   off(r,k) = (r>>4)*1024 + (k>>5)*512 + (((k&31)>>3)*16 + (r&15))*8 + (k&7)
__global__ __launch_bounds__(256) void k_prep(
    const float* __restrict__ S, const float* __restrict__ Q,
    ushort* __restrict__ Sh, ushort* __restrict__ Sl,
    ushort* __restrict__ Qh, ushort* __restrict__ Ql,
    float* __restrict__ sqS) {
  __shared__ float tile[64][65];
  const int tid = threadIdx.x;
  const bool isS = blockIdx.x < 256;
  const int rbase = (blockIdx.x & 255) * 64;
  const float* __restrict__ src = isS ? S : Q;
  ushort* __restrict__ dh = isS ? Sh : Qh;
  ushort* __restrict__ dl = isS ? Sl : Ql;

  const int tx = tid & 63;
  const int ty = tid >> 6;
#pragma unroll
  for (int i = 0; i < 16; ++i) {
    const int r = i * 4 + ty;
    tile[r][tx] = src[(size_t)(rbase + r) * DIM + tx];  // coalesced
  }
  __syncthreads();

  // Panel-swizzled bf16 hi/lo; stores are lane-contiguous 16B.
  const int panel = tid >> 6;           // 0..3
  const int half = (tid >> 5) & 1;      // k-half
  const int slot0 = (tid & 31) * 2;     // slot = q8*16 + m
#pragma unroll
  for (int ss = 0; ss < 2; ++ss) {
    const int s = slot0 + ss;
    const int m = s & 15;
    const int q8 = s >> 4;
    const int row = panel * 16 + m;
    const int kb = half * 32 + q8 * 8;
    short8 hv, lv;
#pragma unroll
    for (int j = 0; j < 8; ++j) {
      const float x = tile[row][kb + j];
      const ushort h = bf16_rne(x);
      const float hf = __uint_as_float(((unsigned)h) << 16);
      hv[j] = (short)h;
      lv[j] = (short)bf16_rne(x - hf);
    }
    const size_t goff =
        (size_t)((rbase >> 4) + panel) * 1024 + (size_t)half * 512 + (size_t)s * 8;
    *(short8*)&dh[goff] = hv;
    *(short8*)&dl[goff] = lv;
  }

  if (isS && tid < 64) {
    float acc = 0.0f;
#pragma unroll
    for (int d = 0; d < DIM; ++d) {
      const float v = tile[tid][d];
      acc = fmaf(v, v, acc);
    }
    sqS[rbase + tid] = acc;
  }
}

// ---------------------------------------------------------------------------
// Phase A: block = 4 waves; wave w: 64 queries x 512 supports.
// grid = (8 splits, 256 q-tiles). 16x16x32 bf16 MFMA; layouts HW-verified
// R4-R10. All fragment loads lane-contiguous (panel storage).
// a accumulates cross - sq/2 (C preloaded with -0.5*sq); block-min of
// key = sq - 2*cross == -2 * block-max of a.

#define MFMA16(A, B, C) __builtin_amdgcn_mfma_f32_16x16x32_bf16(A, B, C, 0, 0, 0)

#define STEP_COMPUTE(H0, H1, L0, L1, SQ)                                   \
  do {                                                                     \
    _Pragma("unroll")                                                      \
    for (int t = 0; t < 4; ++t) {                                          \
      float4v a;                                                           \
      a[0] = -0.5f * SQ.x;                                                 \
      a[1] = -0.5f * SQ.y;                                                 \
      a[2] = -0.5f * SQ.z;                                                 \
      a[3] = -0.5f * SQ.w;                                                 \
      a = MFMA16(H0, qh[t][0], a);                                         \
      a = MFMA16(H1, qh[t][1], a);                                         \
      a = MFMA16(L0, qh[t][0], a);                                         \
      a = MFMA16(L1, qh[t][1], a);                                         \
      a = MFMA16(H0, qlo[t][0], a);                                        \
      a = MFMA16(H1, qlo[t][1], a);                                        \
      bmr[t] = fmaxf(bmr[t], fmaxf(fmaxf(a[0], a[1]), fmaxf(a[2], a[3]))); \
    }                                                                      \
  } while (0)

__global__ __launch_bounds__(256, 3) void k_phaseA(
    const ushort* __restrict__ Sh, const ushort* __restrict__ Sl,
    const ushort* __restrict__ Qh, const ushort* __restrict__ Ql,
    const float* __restrict__ sqS, float* __restrict__ bmin) {
  const int tid = threadIdx.x;
  const int l = tid & 63;
  const int w = tid >> 6;
  const int lm = l & 15;
  const int lq = l >> 4;
  const int split = blockIdx.x;       // 0..7
  const int qbase = blockIdx.y * 64;
  const int sbase = split * 2048 + w * 512;

  // Query (B) fragments, hi and lo: 4 tiles x 2 k-chunks, lane-contiguous.
  // Pinned: the empty asm makes them opaque defs -> compiler must keep them
  // in VGPRs across the loop instead of reloading from global each step.
  short8 qh[4][2], qlo[4][2];
#pragma unroll
  for (int t = 0; t < 4; ++t) {
    const size_t pb = (size_t)((qbase >> 4) + t) * 1024 + (size_t)l * 8;
    qh[t][0] = *(const short8*)&Qh[pb];
    qh[t][1] = *(const short8*)&Qh[pb + 512];
    qlo[t][0] = *(const short8*)&Ql[pb];
    qlo[t][1] = *(const short8*)&Ql[pb + 512];
  }
#pragma unroll
  for (int t = 0; t < 4; ++t) {
    pin8(qh[t][0]);
    pin8(qh[t][1]);
    pin8(qlo[t][0]);
    pin8(qlo[t][1]);
  }

  const ushort* pSh = Sh + (size_t)(sbase >> 4) * 1024 + (size_t)l * 8;
  const ushort* pSl = Sl + (size_t)(sbase >> 4) * 1024 + (size_t)l * 8;
  const float* psq = sqS + sbase + lq * 4;

  // Copy-free double buffer: even steps use (a), odd steps use (b).
  short8 h0a = *(const short8*)(pSh);
  short8 h1a = *(const short8*)(pSh + 512);
  short8 l0a = *(const short8*)(pSl);
  short8 l1a = *(const short8*)(pSl + 512);
  float4 sqa = *(const float4*)(psq);
  short8 h0b = *(const short8*)(pSh + 1024);
  short8 h1b = *(const short8*)(pSh + 1024 + 512);
  short8 l0b = *(const short8*)(pSl + 1024);
  short8 l1b = *(const short8*)(pSl + 1024 + 512);
  float4 sqb = *(const float4*)(psq + 16);

  float bmr[4] = {-FLT_BIG, -FLT_BIG, -FLT_BIG, -FLT_BIG};

  for (int st = 0; st < 32; st += 2) {
    STEP_COMPUTE(h0a, h1a, l0a, l1a, sqa);
    if (st + 2 < 32) {
      const int off = (st + 2) * 1024;
      h0a = *(const short8*)(pSh + off);
      h1a = *(const short8*)(pSh + off + 512);
      l0a = *(const short8*)(pSl + off);
      l1a = *(const short8*)(pSl + off + 512);
      sqa = *(const float4*)(psq + (st + 2) * 16);
    }
    STEP_COMPUTE(h0b, h1b, l0b, l1b, sqb);
    if (st + 3 < 32) {
      const int off = (st + 3) * 1024;
      h0b = *(const short8*)(pSh + off);
      h1b = *(const short8*)(pSh + off + 512);
      l0b = *(const short8*)(pSl + off);
      l1b = *(const short8*)(pSl + off + 512);
      sqb = *(const float4*)(psq + (st + 3) * 16);
    }
    if (((st + 1) & 15) == 15) {  // finished a 256-support block
      const int gb = split * 8 + w * 2 + ((st + 1) >> 4);
#pragma unroll
      for (int t = 0; t < 4; ++t) {
        float v = bmr[t];
        v = fmaxf(v, __shfl_xor(v, 16, 64));
        v = fmaxf(v, __shfl_xor(v, 32, 64));
        if (lq == 0) bmin[(size_t)(qbase + t * 16 + lm) * NSB + gb] = -2.0f * v;
        bmr[t] = -FLT_BIG;
      }
    }
  }
}

// ---------------------------------------------------------------------------
// Phase B: one wave per query; rescore candidate blocks by staging 64x64
// fp32 chunks of ROW-MAJOR S into padded LDS (contiguous 16KB coalesced
// global reads; padded readback = 2-way bank alias, free). No S_T needed.
// Per-wave LDS region: no cross-wave sharing -> no barriers in the loop
// (same-wave DS ops complete in order).
__global__ __launch_bounds__(256) void k_phaseB(
    const float* __restrict__ S,     // [NTOT][64] row-major
    const float* __restrict__ Q,     // [NTOT][64]
    const float* __restrict__ sqS, const float* __restrict__ bmin,
    const float* __restrict__ onehot, float* __restrict__ out) {
  __shared__ float stage[4][64][65];
  __shared__ float sQrow[4][64];
  const int lane = threadIdx.x & 63;
  const int w = threadIdx.x >> 6;
  const int q = blockIdx.x * 4 + w;

  if (lane < 16)
    *(float4*)&sQrow[w][lane * 4] = *(const float4*)&Q[(size_t)q * DIM + lane * 4];
  __syncthreads();

  const float bv = bmin[(size_t)q * NSB + lane];  // lane <-> block
  float m = bv;
#pragma unroll
  for (int d = 1; d < 64; d <<= 1) m = fminf(m, __shfl_xor(m, d, 64));
  unsigned long long msk = __ballot(bv <= m + EPS);

  float bk = FLT_BIG;
  int bi = 0;
  while (msk) {  // ascending block order; wave-uniform control
    const int b = __ffsll((long long)msk) - 1;
    msk &= msk - 1;
#pragma unroll 1
    for (int c = 0; c < 4; ++c) {  // 4 chunks of 64 supports, ascending
      const int cb = b * SBLK + c * 64;
      // Stage: 16KB contiguous, coalesced (j fixed: 4 rows x 256B segments).
#pragma unroll
      for (int j = 0; j < 16; ++j) {
        const int idx = j * 64 + lane;        // float4 index in [0,1024)
        const int row = idx >> 4;
        const int col4 = (idx & 15) << 2;
        *(float4*)&stage[w][row][col4] =
            *(const float4*)&S[(size_t)(cb + row) * DIM + col4];
      }
      // Rescore support cb+lane from LDS row `lane` (exact fp32).
      float a = 0.f;
#pragma unroll
      for (int j = 0; j < 16; ++j) {
        const float4 sv = *(const float4*)&stage[w][lane][j * 4];
        const float4 qv = *(const float4*)&sQrow[w][j * 4];  // broadcast
        a = fmaf(qv.x, sv.x, a);
        a = fmaf(qv.y, sv.y, a);
        a = fmaf(qv.z, sv.z, a);
        a = fmaf(qv.w, sv.w, a);
      }
      const float key = fmaf(-2.f, a, sqS[cb + lane]);
      const int sidx = cb + lane;
      const bool u = key < bk;  // ascending index per lane, strict <
      bk = u ? key : bk;
      bi = u ? sidx : bi;
    }
  }
  // Cross-lane lexicographic argmin on exact keys => first-index semantics.
#pragma unroll
  for (int d = 1; d < 64; d <<= 1) {
    const float ok = __shfl_xor(bk, d, 64);
    const int oi = __shfl_xor(bi, d, 64);
    const bool u = (ok < bk) || (ok == bk && oi < bi);
    bk = u ? ok : bk;
    bi = u ? oi : bi;
  }
  // Label: one-hot rows exact {0,1}; first 1 == np.argmax.
  const float ov = onehot[(size_t)bi * 64 + lane];
  const unsigned long long lmask = __ballot(ov > 0.5f);
  const int label = __ffsll((long long)lmask) - 1;
  out[(size_t)q * 64 + lane] = (lane == label) ? 1.0f : 0.0f;
}

// ---------------------------------------------------------------------------
extern "C" void kernel_launch(void* const* d_in, const int* in_sizes, int n_in,
                              void* d_out, int out_size, void* d_ws, size_t ws_size,
                              hipStream_t stream) {
  const float* S = (const float*)d_in[0];   // [16384][64]
  const float* Q = (const float*)d_in[1];   // [16384][64]
  const float* OH = (const float*)d_in[2];  // [16384][64]
  float* out = (float*)d_out;

  char* ws = (char*)d_ws;
  ushort* Sh = (ushort*)ws;                                  // [0, 2MB)
  ushort* Sl = (ushort*)(ws + (2u << 20));                   // [2, 4MB)
  ushort* Qh = (ushort*)(ws + (4u << 20));                   // [4, 6MB)
  ushort* Ql = (ushort*)(ws + (6u << 20));                   // [6, 8MB)
  float* sqS = (float*)(ws + (8u << 20));                    // 64 KB
  float* bmin = (float*)(ws + (8u << 20) + (64u << 10));     // 4 MB

  k_prep<<<dim3(512), 256, 0, stream>>>(S, Q, Sh, Sl, Qh, Ql, sqS);
  k_phaseA<<<dim3(8, NTOT / 64), 256, 0, stream>>>(Sh, Sl, Qh, Ql, sqS, bmin);
  k_phaseB<<<dim3(NTOT / 4), 256, 0, stream>>>(S, Q, sqS, bmin, OH, out);
  (void)in_sizes; (void)n_in; (void)out_size; (void)ws_size;
}

// Round 12
// 185.145 us; speedup vs baseline: 1.1243x; 1.1243x over previous
//
#include <hip/hip_runtime.h>

// KNN argmin over L2, round 12: best-of recombination.
//  - k_prep: S/Q panels + sqS; if workspace allows (no aliasing needed),
//    ALSO writes S_T in the same pass -> 3 total launches. Otherwise the
//    R10 aliased layout + separate post-phaseA transpose (4 launches).
//  - k_phaseA: R11 version (panel loads, pinned Q-fragments, C init -0.5*sq,
//    copy-free a/b double buffer, launch_bounds(256,3)).
//  - k_phaseB: R10's proven S_T-based coalesced rescore (R11's LDS staging
//    regressed: 8.5M bank conflicts + 66KB LDS -> 17% occupancy).
//
// Filter certification unchanged: 3-term split (sh.qh + sl.qh + sh.ql),
// key error <= ~0.014 << EPS=0.05 => rescore set provably contains the
// true first-argmin support. Phase B compares exact fp32 keys with
// strict-< ascending scan + lexicographic cross-lane reduce => np.argmin
// first-index semantics.

#define NTOT   16384
#define DIM    64
#define SBLK   256                // bmin granularity
#define NSB    (NTOT / SBLK)      // 64
#define EPS    0.05f
#define FLT_BIG 3.4e38f

typedef __attribute__((ext_vector_type(8))) short short8;
typedef __attribute__((ext_vector_type(4))) float float4v;

__device__ __forceinline__ ushort bf16_rne(float x) {
  unsigned u = __float_as_uint(x);
  return (ushort)((u + 0x7FFF + ((u >> 16) & 1)) >> 16);
}

// Opaque def: forbids rematerialization (forces VGPR residency).
__device__ __forceinline__ void pin8(short8& v) {
  asm volatile("" : "+v"(v));
}

// ---------------------------------------------------------------------------
// Fused prep: blocks 0..255 -> S (panels + sqS, optionally S_T);
// blocks 256..511 -> Q (panels only). Panel layout (R8-proven):
//   off(r,k) = (r>>4)*1024 + (k>>5)*512 + (((k&31)>>3)*16 + (r&15))*8 + (k&7)
__global__ __launch_bounds__(256) void k_prep(
    const float* __restrict__ S, const float* __restrict__ Q,
    ushort* __restrict__ Sh, ushort* __restrict__ Sl,
    ushort* __restrict__ Qh, ushort* __restrict__ Ql,
    float* __restrict__ sqS, float* __restrict__ S_T) {
  __shared__ float tile[64][65];
  const int tid = threadIdx.x;
  const bool isS = blockIdx.x < 256;
  const int rbase = (blockIdx.x & 255) * 64;
  const float* __restrict__ src = isS ? S : Q;
  ushort* __restrict__ dh = isS ? Sh : Qh;
  ushort* __restrict__ dl = isS ? Sl : Ql;

  const int tx = tid & 63;
  const int ty = tid >> 6;
#pragma unroll
  for (int i = 0; i < 16; ++i) {
    const int r = i * 4 + ty;
    tile[r][tx] = src[(size_t)(rbase + r) * DIM + tx];  // coalesced
  }
  __syncthreads();

  if (isS && S_T != nullptr) {  // transposed copy (coalesced, pad-safe)
#pragma unroll
    for (int i = 0; i < 16; ++i) {
      const int d = i * 4 + ty;
      S_T[(size_t)d * NTOT + rbase + tx] = tile[tx][d];
    }
  }

  // Panel-swizzled bf16 hi/lo; stores are lane-contiguous 16B.
  const int panel = tid >> 6;           // 0..3
  const int half = (tid >> 5) & 1;      // k-half
  const int slot0 = (tid & 31) * 2;     // slot = q8*16 + m
#pragma unroll
  for (int ss = 0; ss < 2; ++ss) {
    const int s = slot0 + ss;
    const int m = s & 15;
    const int q8 = s >> 4;
    const int row = panel * 16 + m;
    const int kb = half * 32 + q8 * 8;
    short8 hv, lv;
#pragma unroll
    for (int j = 0; j < 8; ++j) {
      const float x = tile[row][kb + j];
      const ushort h = bf16_rne(x);
      const float hf = __uint_as_float(((unsigned)h) << 16);
      hv[j] = (short)h;
      lv[j] = (short)bf16_rne(x - hf);
    }
    const size_t goff =
        (size_t)((rbase >> 4) + panel) * 1024 + (size_t)half * 512 + (size_t)s * 8;
    *(short8*)&dh[goff] = hv;
    *(short8*)&dl[goff] = lv;
  }

  if (isS && tid < 64) {
    float acc = 0.0f;
#pragma unroll
    for (int d = 0; d < DIM; ++d) {
      const float v = tile[tid][d];
      acc = fmaf(v, v, acc);
    }
    sqS[rbase + tid] = acc;
  }
}

// ---------------------------------------------------------------------------
// Standalone transpose (fallback path only; runs AFTER phaseA when S_T
// aliases Sh/Sl).
__global__ __launch_bounds__(256) void k_transpose(
    const float* __restrict__ in, float* __restrict__ outT) {
  __shared__ float tile[64][65];
  const int tx = threadIdx.x & 63;
  const int ty = threadIdx.x >> 6;
  const int rbase = blockIdx.x * 64;
#pragma unroll
  for (int i = 0; i < 16; ++i) {
    const int r = i * 4 + ty;
    tile[r][tx] = in[(size_t)(rbase + r) * DIM + tx];
  }
  __syncthreads();
#pragma unroll
  for (int i = 0; i < 16; ++i) {
    const int d = i * 4 + ty;
    outT[(size_t)d * NTOT + rbase + tx] = tile[tx][d];
  }
}

// ---------------------------------------------------------------------------
// Phase A: block = 4 waves; wave w: 64 queries x 512 supports.
// grid = (8 splits, 256 q-tiles). 16x16x32 bf16 MFMA; layouts HW-verified
// R4-R11. a accumulates cross - sq/2 (C preloaded with -0.5*sq);
// block-min of key = sq - 2*cross == -2 * block-max of a.

#define MFMA16(A, B, C) __builtin_amdgcn_mfma_f32_16x16x32_bf16(A, B, C, 0, 0, 0)

#define STEP_COMPUTE(H0, H1, L0, L1, SQ)                                   \
  do {                                                                     \
    _Pragma("unroll")                                                      \
    for (int t = 0; t < 4; ++t) {                                          \
      float4v a;                                                           \
      a[0] = -0.5f * SQ.x;                                                 \
      a[1] = -0.5f * SQ.y;                                                 \
      a[2] = -0.5f * SQ.z;                                                 \
      a[3] = -0.5f * SQ.w;                                                 \
      a = MFMA16(H0, qh[t][0], a);                                         \
      a = MFMA16(H1, qh[t][1], a);                                         \
      a = MFMA16(L0, qh[t][0], a);                                         \
      a = MFMA16(L1, qh[t][1], a);                                         \
      a = MFMA16(H0, qlo[t][0], a);                                        \
      a = MFMA16(H1, qlo[t][1], a);                                        \
      bmr[t] = fmaxf(bmr[t], fmaxf(fmaxf(a[0], a[1]), fmaxf(a[2], a[3]))); \
    }                                                                      \
  } while (0)

__global__ __launch_bounds__(256, 3) void k_phaseA(
    const ushort* __restrict__ Sh, const ushort* __restrict__ Sl,
    const ushort* __restrict__ Qh, const ushort* __restrict__ Ql,
    const float* __restrict__ sqS, float* __restrict__ bmin) {
  const int tid = threadIdx.x;
  const int l = tid & 63;
  const int w = tid >> 6;
  const int lm = l & 15;
  const int lq = l >> 4;
  const int split = blockIdx.x;       // 0..7
  const int qbase = blockIdx.y * 64;
  const int sbase = split * 2048 + w * 512;

  // Query (B) fragments, hi and lo: pinned in VGPRs (no remat).
  short8 qh[4][2], qlo[4][2];
#pragma unroll
  for (int t = 0; t < 4; ++t) {
    const size_t pb = (size_t)((qbase >> 4) + t) * 1024 + (size_t)l * 8;
    qh[t][0] = *(const short8*)&Qh[pb];
    qh[t][1] = *(const short8*)&Qh[pb + 512];
    qlo[t][0] = *(const short8*)&Ql[pb];
    qlo[t][1] = *(const short8*)&Ql[pb + 512];
  }
#pragma unroll
  for (int t = 0; t < 4; ++t) {
    pin8(qh[t][0]);
    pin8(qh[t][1]);
    pin8(qlo[t][0]);
    pin8(qlo[t][1]);
  }

  const ushort* pSh = Sh + (size_t)(sbase >> 4) * 1024 + (size_t)l * 8;
  const ushort* pSl = Sl + (size_t)(sbase >> 4) * 1024 + (size_t)l * 8;
  const float* psq = sqS + sbase + lq * 4;

  // Copy-free double buffer: even steps use (a), odd steps use (b).
  short8 h0a = *(const short8*)(pSh);
  short8 h1a = *(const short8*)(pSh + 512);
  short8 l0a = *(const short8*)(pSl);
  short8 l1a = *(const short8*)(pSl + 512);
  float4 sqa = *(const float4*)(psq);
  short8 h0b = *(const short8*)(pSh + 1024);
  short8 h1b = *(const short8*)(pSh + 1024 + 512);
  short8 l0b = *(const short8*)(pSl + 1024);
  short8 l1b = *(const short8*)(pSl + 1024 + 512);
  float4 sqb = *(const float4*)(psq + 16);

  float bmr[4] = {-FLT_BIG, -FLT_BIG, -FLT_BIG, -FLT_BIG};

  for (int st = 0; st < 32; st += 2) {
    STEP_COMPUTE(h0a, h1a, l0a, l1a, sqa);
    if (st + 2 < 32) {
      const int off = (st + 2) * 1024;
      h0a = *(const short8*)(pSh + off);
      h1a = *(const short8*)(pSh + off + 512);
      l0a = *(const short8*)(pSl + off);
      l1a = *(const short8*)(pSl + off + 512);
      sqa = *(const float4*)(psq + (st + 2) * 16);
    }
    STEP_COMPUTE(h0b, h1b, l0b, l1b, sqb);
    if (st + 3 < 32) {
      const int off = (st + 3) * 1024;
      h0b = *(const short8*)(pSh + off);
      h1b = *(const short8*)(pSh + off + 512);
      l0b = *(const short8*)(pSl + off);
      l1b = *(const short8*)(pSl + off + 512);
      sqb = *(const float4*)(psq + (st + 3) * 16);
    }
    if (((st + 1) & 15) == 15) {  // finished a 256-support block
      const int gb = split * 8 + w * 2 + ((st + 1) >> 4);
#pragma unroll
      for (int t = 0; t < 4; ++t) {
        float v = bmr[t];
        v = fmaxf(v, __shfl_xor(v, 16, 64));
        v = fmaxf(v, __shfl_xor(v, 32, 64));
        if (lq == 0) bmin[(size_t)(qbase + t * 16 + lm) * NSB + gb] = -2.0f * v;
        bmr[t] = -FLT_BIG;
      }
    }
  }
}

// ---------------------------------------------------------------------------
// Phase B: one wave per query; coalesced rescore from S_T (R10-proven).
__global__ __launch_bounds__(256) void k_phaseB(
    const float* __restrict__ S_T,   // [64][NTOT]
    const float* __restrict__ Q,     // [NTOT][64]
    const float* __restrict__ sqS, const float* __restrict__ bmin,
    const float* __restrict__ onehot, float* __restrict__ out) {
  __shared__ float sQrow[4][64];
  const int lane = threadIdx.x & 63;
  const int w = threadIdx.x >> 6;
  const int q = blockIdx.x * 4 + w;

  if (lane < 16)
    *(float4*)&sQrow[w][lane * 4] = *(const float4*)&Q[(size_t)q * DIM + lane * 4];
  __syncthreads();

  const float bv = bmin[(size_t)q * NSB + lane];  // lane <-> block
  float m = bv;
#pragma unroll
  for (int d = 1; d < 64; d <<= 1) m = fminf(m, __shfl_xor(m, d, 64));
  unsigned long long msk = __ballot(bv <= m + EPS);

  float bk = FLT_BIG;
  int bi = 0;
  while (msk) {  // ascending block order; wave-uniform control
    const int b = __ffsll((long long)msk) - 1;
    msk &= msk - 1;
    const int s0 = b * SBLK + lane * 4;  // 4 consecutive supports per lane
    float a0 = 0.f, a1 = 0.f, a2 = 0.f, a3 = 0.f;
#pragma unroll
    for (int c = 0; c < 16; ++c) {
      const float4 qv = *(const float4*)&sQrow[w][c * 4];  // LDS broadcast
      const float4 s0v = *(const float4*)&S_T[(size_t)(c * 4 + 0) * NTOT + s0];
      const float4 s1v = *(const float4*)&S_T[(size_t)(c * 4 + 1) * NTOT + s0];
      const float4 s2v = *(const float4*)&S_T[(size_t)(c * 4 + 2) * NTOT + s0];
      const float4 s3v = *(const float4*)&S_T[(size_t)(c * 4 + 3) * NTOT + s0];
      a0 = fmaf(qv.x, s0v.x, a0); a1 = fmaf(qv.x, s0v.y, a1);
      a2 = fmaf(qv.x, s0v.z, a2); a3 = fmaf(qv.x, s0v.w, a3);
      a0 = fmaf(qv.y, s1v.x, a0); a1 = fmaf(qv.y, s1v.y, a1);
      a2 = fmaf(qv.y, s1v.z, a2); a3 = fmaf(qv.y, s1v.w, a3);
      a0 = fmaf(qv.z, s2v.x, a0); a1 = fmaf(qv.z, s2v.y, a1);
      a2 = fmaf(qv.z, s2v.z, a2); a3 = fmaf(qv.z, s2v.w, a3);
      a0 = fmaf(qv.w, s3v.x, a0); a1 = fmaf(qv.w, s3v.y, a1);
      a2 = fmaf(qv.w, s3v.z, a2); a3 = fmaf(qv.w, s3v.w, a3);
    }
    const float4 sq4 = *(const float4*)&sqS[s0];
    const float k0 = fmaf(-2.f, a0, sq4.x);
    const float k1 = fmaf(-2.f, a1, sq4.y);
    const float k2 = fmaf(-2.f, a2, sq4.z);
    const float k3 = fmaf(-2.f, a3, sq4.w);
    bool u;  // ascending index, strict < => first minimum per lane
    u = k0 < bk; bk = u ? k0 : bk; bi = u ? s0 : bi;
    u = k1 < bk; bk = u ? k1 : bk; bi = u ? (s0 + 1) : bi;
    u = k2 < bk; bk = u ? k2 : bk; bi = u ? (s0 + 2) : bi;
    u = k3 < bk; bk = u ? k3 : bk; bi = u ? (s0 + 3) : bi;
  }
  // Cross-lane lexicographic argmin on exact keys => first-index semantics.
#pragma unroll
  for (int d = 1; d < 64; d <<= 1) {
    const float ok = __shfl_xor(bk, d, 64);
    const int oi = __shfl_xor(bi, d, 64);
    const bool u = (ok < bk) || (ok == bk && oi < bi);
    bk = u ? ok : bk;
    bi = u ? oi : bi;
  }
  // Label: one-hot rows exact {0,1}; first 1 == np.argmax.
  const float ov = onehot[(size_t)bi * 64 + lane];
  const unsigned long long lmask = __ballot(ov > 0.5f);
  const int label = __ffsll((long long)lmask) - 1;
  out[(size_t)q * 64 + lane] = (lane == label) ? 1.0f : 0.0f;
}

// ---------------------------------------------------------------------------
extern "C" void kernel_launch(void* const* d_in, const int* in_sizes, int n_in,
                              void* d_out, int out_size, void* d_ws, size_t ws_size,
                              hipStream_t stream) {
  const float* S = (const float*)d_in[0];   // [16384][64]
  const float* Q = (const float*)d_in[1];   // [16384][64]
  const float* OH = (const float*)d_in[2];  // [16384][64]
  float* out = (float*)d_out;

  char* ws = (char*)d_ws;
  ushort* Sh = (ushort*)ws;                                  // [0, 2MB)
  ushort* Sl = (ushort*)(ws + (2u << 20));                   // [2, 4MB)
  ushort* Qh = (ushort*)(ws + (4u << 20));                   // [4, 6MB)
  ushort* Ql = (ushort*)(ws + (6u << 20));                   // [6, 8MB)

  // Layout A (ws >= 16.07 MB): dedicated S_T at [8,12MB) -> fused prep,
  // 3 launches. Layout B (proven 12.07 MB): S_T aliases Sh/Sl, transposed
  // after phaseA, 4 launches. ws_size is constant per run -> graph-safe.
  const size_t needA = (16u << 20) + (64u << 10) + 0;  // 16 MB + sqS... (bmin inside)
  const bool bigWs = ws_size >= ((16u << 20) + (64u << 10));
  float* S_T;
  float* sqS;
  float* bmin;
  if (bigWs) {
    S_T = (float*)(ws + (8u << 20));                         // [8, 12MB)
    sqS = (float*)(ws + (12u << 20));                        // 64 KB
    bmin = (float*)(ws + (12u << 20) + (64u << 10));         // 4 MB
  } else {
    S_T = (float*)ws;                                        // aliases Sh+Sl
    sqS = (float*)(ws + (8u << 20));                         // 64 KB
    bmin = (float*)(ws + (8u << 20) + (64u << 10));          // 4 MB
  }
  (void)needA;

  k_prep<<<dim3(512), 256, 0, stream>>>(S, Q, Sh, Sl, Qh, Ql, sqS,
                                        bigWs ? S_T : nullptr);
  k_phaseA<<<dim3(8, NTOT / 64), 256, 0, stream>>>(Sh, Sl, Qh, Ql, sqS, bmin);
  if (!bigWs)
    k_transpose<<<dim3(NTOT / 64), 256, 0, stream>>>(S, S_T);
  k_phaseB<<<dim3(NTOT / 4), 256, 0, stream>>>(S_T, Q, sqS, bmin, OH, out);
  (void)in_sizes; (void)n_in; (void)out_size; (void)ws_size;
}